// Round 4
// baseline (25.161 us; speedup 1.0000x reference)
//
#include <hip/hip_runtime.h>

// EdgeNetwork: messages[e,i] = sum_j relu(edges[e,:] @ W[:, i*32+j] + b[i*32+j]) * states[e,j]
// M = 65536 rows, F=16, D=32.  bf16 MFMA 32x32x16 (K=16==F), swapped operands:
// D[j][e] = sum_f W[f][n*32+j] * edges[e][f]; lane owns one edge (col=lane&31),
// 16 j-values in acc regs (row=(r&3)+8*(r>>2)+4*(lane>>5)) -> relu*state reduce
// is 16 in-register FMAs + one shfl_xor(32).
//
// Round-4 changes: prep kernel converts W/bias into frag order in d_ws ONCE
// (round 3 re-staged + re-converted W per block: ~900 VALU-cyc/wave + 8-way
// LDS write conflicts before a barrier). Main kernel has NO LDS and NO barrier:
// afrag = coalesced 16B/lane load from L2-resident ws (64 MB L2 traffic ~2 us),
// bias = broadcast lines. Keeps round-3's anti-spill skeleton: (512,2) -> 128
// VGPR budget (round-2's 64-clamp caused 220 MB scratch), two 8-k loops,
// unroll 4 to bound load-hoist live range.

typedef __attribute__((ext_vector_type(8))) short short8;
typedef __attribute__((ext_vector_type(16))) float f32x16;

#define WS_BYTES 36864   // 32768 B W-frags (bf16) + 4096 B bias-frags (f32)

__device__ __forceinline__ unsigned short f2bf(float x) {
    union { float f; unsigned u; } v; v.f = x;
    return (unsigned short)((v.u + 0x7FFFu + ((v.u >> 16) & 1u)) >> 16);  // RNE
}

// ---- prep: W -> bf16 A-frag order, bias -> f32 C-frag order, into ws ----
// wf idx ((n*64 + l)*8 + t) = bf16(W[f][n*32 + j]), l = j + (f>>3)*32, t = f&7
// bf idx (n*32 + h*16 + r)  = bias[n*32 + (r&3) + 8*(r>>2) + 4*h]
__global__ __launch_bounds__(256)
void edgenet_prep(const float* __restrict__ W, const float* __restrict__ bias,
                  void* __restrict__ ws)
{
    const int idx = blockIdx.x * 256 + threadIdx.x;   // 68*256 = 17408 exact
    unsigned short* wf = (unsigned short*)ws;
    float* bf = (float*)((char*)ws + 32768);
    if (idx < 16384) {
        const int f = idx >> 10, c = idx & 1023, n = c >> 5, j = c & 31;
        wf[((n << 6) + j + ((f >> 3) << 5)) * 8 + (f & 7)] = f2bf(W[idx]);
    } else {
        const int t = idx - 16384;                    // 0..1023
        const int r = t & 15, hh = (t >> 4) & 1, n = t >> 5;
        bf[t] = bias[(n << 5) + (r & 3) + ((r >> 2) << 3) + (hh << 2)];
    }
}

// ---- main: no LDS, no barrier; frags stream from L2-resident ws ----
__global__ __launch_bounds__(512, 2)
void edgenet_main(const float* __restrict__ states,
                  const float* __restrict__ edges,
                  float* __restrict__ out,
                  const void* __restrict__ ws)
{
    const unsigned short* __restrict__ wf = (const unsigned short*)ws;
    const float* __restrict__ bf = (const float*)((const char*)ws + 32768);

    const int tid  = threadIdx.x;
    const int wave = tid >> 6;
    const int lane = tid & 63;
    const int ecol = lane & 31;
    const int h    = lane >> 5;

    const int tile  = blockIdx.x * 4 + (wave >> 1);   // 512 blocks * 4 = 2048 tiles
    const int nbase = (wave & 1) << 4;                // 0 or 16
    const long long row = (long long)tile * 32 + ecol;

    // ---- edges row -> B fragment: B[k=h*8+t][col=ecol] = edges[row][h*8+t] ----
    const float* ep = edges + row * 16 + h * 8;
    const float4 ev0 = *reinterpret_cast<const float4*>(ep);
    const float4 ev1 = *reinterpret_cast<const float4*>(ep + 4);
    short8 bfrag;
    bfrag[0] = (short)f2bf(ev0.x); bfrag[1] = (short)f2bf(ev0.y);
    bfrag[2] = (short)f2bf(ev0.z); bfrag[3] = (short)f2bf(ev0.w);
    bfrag[4] = (short)f2bf(ev1.x); bfrag[5] = (short)f2bf(ev1.y);
    bfrag[6] = (short)f2bf(ev1.z); bfrag[7] = (short)f2bf(ev1.w);

    // s[r] = states[row][(r>>2)*8 + h*4 + (r&3)]  (matches acc reg r)
    const float* sp = states + row * 32 + h * 4;
    const float4 sv0 = *reinterpret_cast<const float4*>(sp);
    const float4 sv1 = *reinterpret_cast<const float4*>(sp + 8);
    const float4 sv2 = *reinterpret_cast<const float4*>(sp + 16);
    const float4 sv3 = *reinterpret_cast<const float4*>(sp + 24);
    const float s[16] = {sv0.x, sv0.y, sv0.z, sv0.w,
                         sv1.x, sv1.y, sv1.z, sv1.w,
                         sv2.x, sv2.y, sv2.z, sv2.w,
                         sv3.x, sv3.y, sv3.z, sv3.w};

    // per-lane A-frag base for n=nbase: elements ((nbase*64)+lane)*8, +512 per n
    const unsigned short* __restrict__ wl = wf + (((unsigned)nbase << 6) + (unsigned)lane) * 8;
    const float* __restrict__ bb = bf + (nbase << 5) + (h << 4);

    float msg[8];

    // ---- half A: n = nbase + kk, result stored by h==0 lanes ----
    #pragma unroll 4
    for (int kk = 0; kk < 8; ++kk) {
        const short8 afrag = *reinterpret_cast<const short8*>(wl + kk * 512);
        const float4 c0 = *reinterpret_cast<const float4*>(bb + kk * 32);
        const float4 c1 = *reinterpret_cast<const float4*>(bb + kk * 32 + 4);
        const float4 c2 = *reinterpret_cast<const float4*>(bb + kk * 32 + 8);
        const float4 c3 = *reinterpret_cast<const float4*>(bb + kk * 32 + 12);
        f32x16 acc;
        acc[0]=c0.x;  acc[1]=c0.y;  acc[2]=c0.z;  acc[3]=c0.w;
        acc[4]=c1.x;  acc[5]=c1.y;  acc[6]=c1.z;  acc[7]=c1.w;
        acc[8]=c2.x;  acc[9]=c2.y;  acc[10]=c2.z; acc[11]=c2.w;
        acc[12]=c3.x; acc[13]=c3.y; acc[14]=c3.z; acc[15]=c3.w;
        acc = __builtin_amdgcn_mfma_f32_32x32x16_bf16(afrag, bfrag, acc, 0, 0, 0);
        float p0 = 0.f, p1 = 0.f, p2 = 0.f, p3 = 0.f;
        #pragma unroll
        for (int r = 0; r < 16; r += 4) {
            p0 = fmaf(fmaxf(acc[r+0], 0.f), s[r+0], p0);
            p1 = fmaf(fmaxf(acc[r+1], 0.f), s[r+1], p1);
            p2 = fmaf(fmaxf(acc[r+2], 0.f), s[r+2], p2);
            p3 = fmaf(fmaxf(acc[r+3], 0.f), s[r+3], p3);
        }
        float p = (p0 + p1) + (p2 + p3);
        p += __shfl_xor(p, 32);
        msg[kk] = p;
    }
    if (h == 0) {
        float* op = out + row * 32 + nbase;
        *reinterpret_cast<float4*>(op)     = make_float4(msg[0], msg[1], msg[2], msg[3]);
        *reinterpret_cast<float4*>(op + 4) = make_float4(msg[4], msg[5], msg[6], msg[7]);
    }

    // ---- half B: n = nbase + 8 + kk, result stored by h==1 lanes ----
    #pragma unroll 4
    for (int kk = 0; kk < 8; ++kk) {
        const short8 afrag = *reinterpret_cast<const short8*>(wl + (8 + kk) * 512);
        const float4 c0 = *reinterpret_cast<const float4*>(bb + (8 + kk) * 32);
        const float4 c1 = *reinterpret_cast<const float4*>(bb + (8 + kk) * 32 + 4);
        const float4 c2 = *reinterpret_cast<const float4*>(bb + (8 + kk) * 32 + 8);
        const float4 c3 = *reinterpret_cast<const float4*>(bb + (8 + kk) * 32 + 12);
        f32x16 acc;
        acc[0]=c0.x;  acc[1]=c0.y;  acc[2]=c0.z;  acc[3]=c0.w;
        acc[4]=c1.x;  acc[5]=c1.y;  acc[6]=c1.z;  acc[7]=c1.w;
        acc[8]=c2.x;  acc[9]=c2.y;  acc[10]=c2.z; acc[11]=c2.w;
        acc[12]=c3.x; acc[13]=c3.y; acc[14]=c3.z; acc[15]=c3.w;
        acc = __builtin_amdgcn_mfma_f32_32x32x16_bf16(afrag, bfrag, acc, 0, 0, 0);
        float p0 = 0.f, p1 = 0.f, p2 = 0.f, p3 = 0.f;
        #pragma unroll
        for (int r = 0; r < 16; r += 4) {
            p0 = fmaf(fmaxf(acc[r+0], 0.f), s[r+0], p0);
            p1 = fmaf(fmaxf(acc[r+1], 0.f), s[r+1], p1);
            p2 = fmaf(fmaxf(acc[r+2], 0.f), s[r+2], p2);
            p3 = fmaf(fmaxf(acc[r+3], 0.f), s[r+3], p3);
        }
        float p = (p0 + p1) + (p2 + p3);
        p += __shfl_xor(p, 32);
        msg[kk] = p;
    }
    if (h == 1) {
        float* op = out + row * 32 + nbase + 8;
        *reinterpret_cast<float4*>(op)     = make_float4(msg[0], msg[1], msg[2], msg[3]);
        *reinterpret_cast<float4*>(op + 4) = make_float4(msg[4], msg[5], msg[6], msg[7]);
    }
}

// ---- fallback (ws too small): round-3 kernel, per-block LDS staging ----
__global__ __launch_bounds__(512, 2)
void edgenet_fallback(const float* __restrict__ states, const float* __restrict__ edges,
                      const float* __restrict__ W, const float* __restrict__ bias,
                      float* __restrict__ out)
{
    __shared__ unsigned short Wlds[16384];
    __shared__ float Blds[1024];
    const int tid  = threadIdx.x;
    const int wave = tid >> 6;
    const int lane = tid & 63;
    const int ecol = lane & 31;
    const int h    = lane >> 5;
    const int tile  = blockIdx.x * 4 + (wave >> 1);
    const int nbase = (wave & 1) << 4;
    const long long row = (long long)tile * 32 + ecol;

    const float* ep = edges + row * 16 + h * 8;
    const float4 ev0 = *reinterpret_cast<const float4*>(ep);
    const float4 ev1 = *reinterpret_cast<const float4*>(ep + 4);
    const float* sp = states + row * 32 + h * 4;
    const float4 sv0 = *reinterpret_cast<const float4*>(sp);
    const float4 sv1 = *reinterpret_cast<const float4*>(sp + 8);
    const float4 sv2 = *reinterpret_cast<const float4*>(sp + 16);
    const float4 sv3 = *reinterpret_cast<const float4*>(sp + 24);

    #pragma unroll
    for (int it = 0; it < 32; ++it) {
        int m = it * 512 + tid;
        int f = m >> 10, c = m & 1023, n = c >> 5, j = c & 31;
        Wlds[((n << 6) + j + ((f >> 3) << 5)) * 8 + (f & 7)] = f2bf(W[m]);
    }
    {
        int i0 = tid;
        int r = i0 & 15, hh = (i0 >> 4) & 1, n = i0 >> 5;
        Blds[i0] = bias[(n << 5) + (r & 3) + ((r >> 2) << 3) + (hh << 2)];
        int i1 = tid + 512;
        r = i1 & 15; hh = (i1 >> 4) & 1; n = i1 >> 5;
        Blds[i1] = bias[(n << 5) + (r & 3) + ((r >> 2) << 3) + (hh << 2)];
    }
    __syncthreads();

    short8 bfrag;
    bfrag[0] = (short)f2bf(ev0.x); bfrag[1] = (short)f2bf(ev0.y);
    bfrag[2] = (short)f2bf(ev0.z); bfrag[3] = (short)f2bf(ev0.w);
    bfrag[4] = (short)f2bf(ev1.x); bfrag[5] = (short)f2bf(ev1.y);
    bfrag[6] = (short)f2bf(ev1.z); bfrag[7] = (short)f2bf(ev1.w);
    const float s[16] = {sv0.x, sv0.y, sv0.z, sv0.w,
                         sv1.x, sv1.y, sv1.z, sv1.w,
                         sv2.x, sv2.y, sv2.z, sv2.w,
                         sv3.x, sv3.y, sv3.z, sv3.w};
    const unsigned short* wl = &Wlds[(((unsigned)nbase << 6) + (unsigned)lane) << 3];
    const float* bb = &Blds[(nbase << 5) + (h << 4)];
    float msg[8];

    #pragma unroll 4
    for (int kk = 0; kk < 8; ++kk) {
        f32x16 acc;
        #pragma unroll
        for (int r = 0; r < 16; ++r) acc[r] = bb[kk * 32 + r];
        const short8 afrag = *reinterpret_cast<const short8*>(wl + kk * 512);
        acc = __builtin_amdgcn_mfma_f32_32x32x16_bf16(afrag, bfrag, acc, 0, 0, 0);
        float p0 = 0.f, p1 = 0.f, p2 = 0.f, p3 = 0.f;
        #pragma unroll
        for (int r = 0; r < 16; r += 4) {
            p0 = fmaf(fmaxf(acc[r+0], 0.f), s[r+0], p0);
            p1 = fmaf(fmaxf(acc[r+1], 0.f), s[r+1], p1);
            p2 = fmaf(fmaxf(acc[r+2], 0.f), s[r+2], p2);
            p3 = fmaf(fmaxf(acc[r+3], 0.f), s[r+3], p3);
        }
        float p = (p0 + p1) + (p2 + p3);
        p += __shfl_xor(p, 32);
        msg[kk] = p;
    }
    if (h == 0) {
        float* op = out + row * 32 + nbase;
        *reinterpret_cast<float4*>(op)     = make_float4(msg[0], msg[1], msg[2], msg[3]);
        *reinterpret_cast<float4*>(op + 4) = make_float4(msg[4], msg[5], msg[6], msg[7]);
    }
    #pragma unroll 4
    for (int kk = 0; kk < 8; ++kk) {
        f32x16 acc;
        #pragma unroll
        for (int r = 0; r < 16; ++r) acc[r] = bb[(8 + kk) * 32 + r];
        const short8 afrag = *reinterpret_cast<const short8*>(wl + (8 + kk) * 512);
        acc = __builtin_amdgcn_mfma_f32_32x32x16_bf16(afrag, bfrag, acc, 0, 0, 0);
        float p0 = 0.f, p1 = 0.f, p2 = 0.f, p3 = 0.f;
        #pragma unroll
        for (int r = 0; r < 16; r += 4) {
            p0 = fmaf(fmaxf(acc[r+0], 0.f), s[r+0], p0);
            p1 = fmaf(fmaxf(acc[r+1], 0.f), s[r+1], p1);
            p2 = fmaf(fmaxf(acc[r+2], 0.f), s[r+2], p2);
            p3 = fmaf(fmaxf(acc[r+3], 0.f), s[r+3], p3);
        }
        float p = (p0 + p1) + (p2 + p3);
        p += __shfl_xor(p, 32);
        msg[kk] = p;
    }
    if (h == 1) {
        float* op = out + row * 32 + nbase + 8;
        *reinterpret_cast<float4*>(op)     = make_float4(msg[0], msg[1], msg[2], msg[3]);
        *reinterpret_cast<float4*>(op + 4) = make_float4(msg[4], msg[5], msg[6], msg[7]);
    }
}

extern "C" void kernel_launch(void* const* d_in, const int* in_sizes, int n_in,
                              void* d_out, int out_size, void* d_ws, size_t ws_size,
                              hipStream_t stream) {
    (void)in_sizes; (void)n_in; (void)out_size;
    const float* states = (const float*)d_in[0];
    const float* edges  = (const float*)d_in[1];
    const float* W      = (const float*)d_in[2];
    const float* bias   = (const float*)d_in[3];
    float* out          = (float*)d_out;

    if (ws_size >= (size_t)WS_BYTES) {
        hipLaunchKernelGGL(edgenet_prep, dim3(68), dim3(256), 0, stream, W, bias, d_ws);
        hipLaunchKernelGGL(edgenet_main, dim3(512), dim3(512), 0, stream,
                           states, edges, out, d_ws);
    } else {
        hipLaunchKernelGGL(edgenet_fallback, dim3(512), dim3(512), 0, stream,
                           states, edges, W, bias, out);
    }
}

// Round 5
// 19.459 us; speedup vs baseline: 1.2930x; 1.2930x over previous
//
#include <hip/hip_runtime.h>

// EdgeNetwork: messages[e,i] = sum_j relu(edges[e,:] @ W[:, i*32+j] + b[i*32+j]) * states[e,j]
// M = 65536 rows, F=16, D=32.
//
// Round-5 redesign: per j in [0,32), one bf16 MFMA 32x32x16 computes
// D_j[e][n] = sum_f edges[e][f] * W[f][n*32+j]   (A = edges tile, B = W-slice j)
// Output mapping (verified m74/m101): col n = lane&31, row e = (r&3)+8*(r>>2)+4*(lane>>5).
// msg accumulates IN-REGISTER across j:  p[r] += relu(D+bias[n*32+j]) * states[e][j].
// -> no per-k shuffle (round 3/4's lgkm serializer), no msg selects, bias = 1 scalar/j.
// C operand = persistent zero16 tuple (no per-j acc-init movs).
// W/bias pre-fragmented by prep kernel into d_ws; main bulk-copies 36 KB -> LDS linearly.
// Tile's j-range split across 2 waves; partials combined via LDS (aliased on s-tile).

typedef __attribute__((ext_vector_type(8))) short short8;
typedef __attribute__((ext_vector_type(16))) float f32x16;

#define WS_BYTES 36864   // 32768 B W-frags (bf16) + 4096 B bias (f32, transposed)

__device__ __forceinline__ unsigned short f2bf(float x) {
    union { float f; unsigned u; } v; v.f = x;
    return (unsigned short)((v.u + 0x7FFFu + ((v.u >> 16) & 1u)) >> 16);  // RNE
}

// ---- prep: W -> bf16 B-frag order, bias -> transposed f32, into ws ----
// wf[((j*64 + l)*8 + t)] = bf16(W[f][n*32+j]),  l = n + (f>>3)*32, t = f&7
// bf[j*32 + n] = bias[n*32 + j]
__global__ __launch_bounds__(256)
void edgenet_prep(const float* __restrict__ W, const float* __restrict__ bias,
                  void* __restrict__ ws)
{
    const int idx = blockIdx.x * 256 + threadIdx.x;   // 68*256 = 17408 exact
    unsigned short* wf = (unsigned short*)ws;
    float* bf = (float*)((char*)ws + 32768);
    if (idx < 16384) {
        const int f = idx >> 10, c = idx & 1023;
        const int j = c & 31, n = c >> 5;
        const int l = n + ((f >> 3) << 5);
        wf[(((j << 6) + l) << 3) + (f & 7)] = f2bf(W[idx]);
    } else {
        const int q = idx - 16384;                    // q = j*32 + n
        bf[q] = bias[((q & 31) << 5) + (q >> 5)];
    }
}

__global__ __launch_bounds__(512, 2)
void edgenet_main(const float* __restrict__ states,
                  const float* __restrict__ edges,
                  float* __restrict__ out,
                  const void* __restrict__ ws)
{
    __shared__ unsigned char Wb[36864];     // [0,32768): W frags bf16; [32768,): bias f32
    __shared__ float s_lds[4][1024];        // s_lds[tl][j*32 + e]; reused as combine buf

    const int tid  = threadIdx.x;
    const int wave = tid >> 6;
    const int lane = tid & 63;
    const int n    = lane & 31;             // output column i
    const int h    = lane >> 5;
    const int tl    = wave >> 1;            // tile within block (0..3)
    const int jhalf = wave & 1;             // 0: j 0..15, 1: j 16..31
    const int tile  = blockIdx.x * 4 + tl;  // 512 blocks * 4 = 2048 tiles
    const int jbase = jhalf << 4;

    // ---- stage W+bias: linear 16B copy ws -> LDS (2304 chunks) ----
    {
        const char* g = (const char*)ws;
        #pragma unroll
        for (int i = 0; i < 4; ++i) {
            const int off = (i * 512 + tid) * 16;
            *reinterpret_cast<float4*>(&Wb[off]) = *reinterpret_cast<const float4*>(g + off);
        }
        if (tid < 256) {
            const int off = (2048 + tid) * 16;
            *reinterpret_cast<float4*>(&Wb[off]) = *reinterpret_cast<const float4*>(g + off);
        }
    }

    // ---- stage states transposed: 128 threads per tile; s_lds[tl][j*32+e] ----
    {
        const int u = tid & 127, mytl = tid >> 7;
        const int e = u & 31, jq = u >> 5;            // jq = 0..3
        const float* sp = states + ((long long)(blockIdx.x * 4 + mytl) * 32 + e) * 32 + jq * 8;
        const float4 a = *reinterpret_cast<const float4*>(sp);
        const float4 b = *reinterpret_cast<const float4*>(sp + 4);
        float* d = &s_lds[mytl][(jq * 8) * 32 + e];   // stride 32 per j
        d[0 * 32] = a.x; d[1 * 32] = a.y; d[2 * 32] = a.z; d[3 * 32] = a.w;
        d[4 * 32] = b.x; d[5 * 32] = b.y; d[6 * 32] = b.z; d[7 * 32] = b.w;
    }

    // ---- edges A-frag: lane holds edges[tile*32 + n][h*8 .. h*8+7] ----
    const long long erow = (long long)tile * 32 + n;
    const float* ep = edges + erow * 16 + h * 8;
    const float4 ev0 = *reinterpret_cast<const float4*>(ep);
    const float4 ev1 = *reinterpret_cast<const float4*>(ep + 4);
    short8 afrag;
    afrag[0] = (short)f2bf(ev0.x); afrag[1] = (short)f2bf(ev0.y);
    afrag[2] = (short)f2bf(ev0.z); afrag[3] = (short)f2bf(ev0.w);
    afrag[4] = (short)f2bf(ev1.x); afrag[5] = (short)f2bf(ev1.y);
    afrag[6] = (short)f2bf(ev1.z); afrag[7] = (short)f2bf(ev1.w);

    __syncthreads();

    const unsigned short* wl = (const unsigned short*)&Wb[0];
    const float* bl = (const float*)&Wb[32768];
    const float* st = &s_lds[tl][0];

    f32x16 zero16;
    #pragma unroll
    for (int r = 0; r < 16; ++r) zero16[r] = 0.f;

    float p[16];
    #pragma unroll
    for (int r = 0; r < 16; ++r) p[r] = 0.f;

    const int h4 = h << 2;

    #pragma unroll 2
    for (int jj = 0; jj < 16; ++jj) {
        const int j = jbase + jj;
        // B-frag for slice j: one conflict-free ds_read_b128 per lane
        const short8 wfrag = *reinterpret_cast<const short8*>(wl + (((j << 6) + lane) << 3));
        const float bj = bl[(j << 5) + n];
        // states broadcast: s[e][j] for this half's e-set {4h+8q+0..3}
        const float4 s0 = *reinterpret_cast<const float4*>(st + (j << 5) + h4);
        const float4 s1 = *reinterpret_cast<const float4*>(st + (j << 5) + h4 + 8);
        const float4 s2 = *reinterpret_cast<const float4*>(st + (j << 5) + h4 + 16);
        const float4 s3 = *reinterpret_cast<const float4*>(st + (j << 5) + h4 + 24);

        const f32x16 acc = __builtin_amdgcn_mfma_f32_32x32x16_bf16(afrag, wfrag, zero16, 0, 0, 0);

        p[0]  = fmaf(fmaxf(acc[0]  + bj, 0.f), s0.x, p[0]);
        p[1]  = fmaf(fmaxf(acc[1]  + bj, 0.f), s0.y, p[1]);
        p[2]  = fmaf(fmaxf(acc[2]  + bj, 0.f), s0.z, p[2]);
        p[3]  = fmaf(fmaxf(acc[3]  + bj, 0.f), s0.w, p[3]);
        p[4]  = fmaf(fmaxf(acc[4]  + bj, 0.f), s1.x, p[4]);
        p[5]  = fmaf(fmaxf(acc[5]  + bj, 0.f), s1.y, p[5]);
        p[6]  = fmaf(fmaxf(acc[6]  + bj, 0.f), s1.z, p[6]);
        p[7]  = fmaf(fmaxf(acc[7]  + bj, 0.f), s1.w, p[7]);
        p[8]  = fmaf(fmaxf(acc[8]  + bj, 0.f), s2.x, p[8]);
        p[9]  = fmaf(fmaxf(acc[9]  + bj, 0.f), s2.y, p[9]);
        p[10] = fmaf(fmaxf(acc[10] + bj, 0.f), s2.z, p[10]);
        p[11] = fmaf(fmaxf(acc[11] + bj, 0.f), s2.w, p[11]);
        p[12] = fmaf(fmaxf(acc[12] + bj, 0.f), s3.x, p[12]);
        p[13] = fmaf(fmaxf(acc[13] + bj, 0.f), s3.y, p[13]);
        p[14] = fmaf(fmaxf(acc[14] + bj, 0.f), s3.z, p[14]);
        p[15] = fmaf(fmaxf(acc[15] + bj, 0.f), s3.w, p[15]);
    }

    // ---- combine the two j-halves via LDS (alias s_lds, dead after loop) ----
    __syncthreads();                         // all s_lds reads done
    float* ob = &s_lds[tl][0];
    if (jhalf == 1) {
        #pragma unroll
        for (int r = 0; r < 16; ++r) {
            const int e = (r & 3) + ((r >> 2) << 3) + h4;
            ob[(e << 5) + n] = p[r];         // bank = n: 2 lanes/bank (h pair) = free
        }
    }
    __syncthreads();
    if (jhalf == 0) {
        float* op = out + ((long long)tile * 32) * 32;
        #pragma unroll
        for (int r = 0; r < 16; ++r) {
            const int e = (r & 3) + ((r >> 2) << 3) + h4;
            op[(e << 5) + n] = p[r] + ob[(e << 5) + n];   // 2 x 128B lines per instr
        }
    }
}

// ---- fallback (ws too small): round-3 kernel (measured 20.9 us) ----
__global__ __launch_bounds__(512, 2)
void edgenet_fallback(const float* __restrict__ states, const float* __restrict__ edges,
                      const float* __restrict__ W, const float* __restrict__ bias,
                      float* __restrict__ out)
{
    __shared__ unsigned short Wlds[16384];
    __shared__ float Blds[1024];
    const int tid  = threadIdx.x;
    const int wave = tid >> 6;
    const int lane = tid & 63;
    const int ecol = lane & 31;
    const int h    = lane >> 5;
    const int tile  = blockIdx.x * 4 + (wave >> 1);
    const int nbase = (wave & 1) << 4;
    const long long row = (long long)tile * 32 + ecol;

    const float* ep = edges + row * 16 + h * 8;
    const float4 ev0 = *reinterpret_cast<const float4*>(ep);
    const float4 ev1 = *reinterpret_cast<const float4*>(ep + 4);
    const float* sp = states + row * 32 + h * 4;
    const float4 sv0 = *reinterpret_cast<const float4*>(sp);
    const float4 sv1 = *reinterpret_cast<const float4*>(sp + 8);
    const float4 sv2 = *reinterpret_cast<const float4*>(sp + 16);
    const float4 sv3 = *reinterpret_cast<const float4*>(sp + 24);

    #pragma unroll
    for (int it = 0; it < 32; ++it) {
        int m = it * 512 + tid;
        int f = m >> 10, c = m & 1023, nn = c >> 5, j = c & 31;
        Wlds[((nn << 6) + j + ((f >> 3) << 5)) * 8 + (f & 7)] = f2bf(W[m]);
    }
    {
        int i0 = tid;
        int r = i0 & 15, hh = (i0 >> 4) & 1, nn = i0 >> 5;
        Blds[i0] = bias[(nn << 5) + (r & 3) + ((r >> 2) << 3) + (hh << 2)];
        int i1 = tid + 512;
        r = i1 & 15; hh = (i1 >> 4) & 1; nn = i1 >> 5;
        Blds[i1] = bias[(nn << 5) + (r & 3) + ((r >> 2) << 3) + (hh << 2)];
    }
    __syncthreads();

    short8 bfrag;
    bfrag[0] = (short)f2bf(ev0.x); bfrag[1] = (short)f2bf(ev0.y);
    bfrag[2] = (short)f2bf(ev0.z); bfrag[3] = (short)f2bf(ev0.w);
    bfrag[4] = (short)f2bf(ev1.x); bfrag[5] = (short)f2bf(ev1.y);
    bfrag[6] = (short)f2bf(ev1.z); bfrag[7] = (short)f2bf(ev1.w);
    const float s[16] = {sv0.x, sv0.y, sv0.z, sv0.w,
                         sv1.x, sv1.y, sv1.z, sv1.w,
                         sv2.x, sv2.y, sv2.z, sv2.w,
                         sv3.x, sv3.y, sv3.z, sv3.w};
    const unsigned short* wl = &Wlds[(((unsigned)nbase << 6) + (unsigned)lane) << 3];
    const float* bb = &Blds[(nbase << 5) + (h << 4)];
    float msg[8];

    #pragma unroll 4
    for (int kk = 0; kk < 8; ++kk) {
        f32x16 acc;
        #pragma unroll
        for (int r = 0; r < 16; ++r) acc[r] = bb[kk * 32 + r];
        const short8 afrag = *reinterpret_cast<const short8*>(wl + kk * 512);
        acc = __builtin_amdgcn_mfma_f32_32x32x16_bf16(afrag, bfrag, acc, 0, 0, 0);
        float p0 = 0.f, p1 = 0.f, p2 = 0.f, p3 = 0.f;
        #pragma unroll
        for (int r = 0; r < 16; r += 4) {
            p0 = fmaf(fmaxf(acc[r+0], 0.f), s[r+0], p0);
            p1 = fmaf(fmaxf(acc[r+1], 0.f), s[r+1], p1);
            p2 = fmaf(fmaxf(acc[r+2], 0.f), s[r+2], p2);
            p3 = fmaf(fmaxf(acc[r+3], 0.f), s[r+3], p3);
        }
        float p = (p0 + p1) + (p2 + p3);
        p += __shfl_xor(p, 32);
        msg[kk] = p;
    }
    if (h == 0) {
        float* op = out + row * 32 + nbase;
        *reinterpret_cast<float4*>(op)     = make_float4(msg[0], msg[1], msg[2], msg[3]);
        *reinterpret_cast<float4*>(op + 4) = make_float4(msg[4], msg[5], msg[6], msg[7]);
    }
    #pragma unroll 4
    for (int kk = 0; kk < 8; ++kk) {
        f32x16 acc;
        #pragma unroll
        for (int r = 0; r < 16; ++r) acc[r] = bb[(8 + kk) * 32 + r];
        const short8 afrag = *reinterpret_cast<const short8*>(wl + (8 + kk) * 512);
        acc = __builtin_amdgcn_mfma_f32_32x32x16_bf16(afrag, bfrag, acc, 0, 0, 0);
        float p0 = 0.f, p1 = 0.f, p2 = 0.f, p3 = 0.f;
        #pragma unroll
        for (int r = 0; r < 16; r += 4) {
            p0 = fmaf(fmaxf(acc[r+0], 0.f), s[r+0], p0);
            p1 = fmaf(fmaxf(acc[r+1], 0.f), s[r+1], p1);
            p2 = fmaf(fmaxf(acc[r+2], 0.f), s[r+2], p2);
            p3 = fmaf(fmaxf(acc[r+3], 0.f), s[r+3], p3);
        }
        float p = (p0 + p1) + (p2 + p3);
        p += __shfl_xor(p, 32);
        msg[kk] = p;
    }
    if (h == 1) {
        float* op = out + row * 32 + nbase + 8;
        *reinterpret_cast<float4*>(op)     = make_float4(msg[0], msg[1], msg[2], msg[3]);
        *reinterpret_cast<float4*>(op + 4) = make_float4(msg[4], msg[5], msg[6], msg[7]);
    }
}

extern "C" void kernel_launch(void* const* d_in, const int* in_sizes, int n_in,
                              void* d_out, int out_size, void* d_ws, size_t ws_size,
                              hipStream_t stream) {
    (void)in_sizes; (void)n_in; (void)out_size;
    const float* states = (const float*)d_in[0];
    const float* edges  = (const float*)d_in[1];
    const float* W      = (const float*)d_in[2];
    const float* bias   = (const float*)d_in[3];
    float* out          = (float*)d_out;

    if (ws_size >= (size_t)WS_BYTES) {
        hipLaunchKernelGGL(edgenet_prep, dim3(68), dim3(256), 0, stream, W, bias, d_ws);
        hipLaunchKernelGGL(edgenet_main, dim3(512), dim3(512), 0, stream,
                           states, edges, out, d_ws);
    } else {
        hipLaunchKernelGGL(edgenet_fallback, dim3(512), dim3(512), 0, stream,
                           states, edges, W, bias, out);
    }
}

// Round 6
// 19.285 us; speedup vs baseline: 1.3047x; 1.0091x over previous
//
#include <hip/hip_runtime.h>

// EdgeNetwork: messages[e,i] = sum_j relu(edges[e,:] @ W[:, i*32+j] + b[i*32+j]) * states[e,j]
// M = 65536 rows, F=16, D=32.
//
// Structure (round-5 winner, 19.5 us): per j in [0,32), one bf16 MFMA 32x32x16:
// D_j[e][n] = sum_f edges[e][f] * W[f][n*32+j]  (A = edges tile, B = W-slice j).
// Output mapping: col n = lane&31, row e = (r&3)+8*(r>>2)+4*(lane>>5).
// msg accumulates in-register across j: p[r] += relu(D+bias[n*32+j]) * states[e][j].
// W/bias pre-fragmented by prep kernel into d_ws; main bulk-copies 36 KB -> LDS.
// Tile's j-range split across 2 waves; partials combined via LDS.
//
// Round-6 change (single lever): __launch_bounds__(512,3) -> VGPR cap 85,
// 3 blocks/CU (LDS 3*52KB = 159.7KB fits), 24 waves/CU (was 16). Round-5 was
// stall-bound: every floor (HBM 3.2us, VALU 2.6us, LDS-pipe ~6us) is far below
// the ~16us main-kernel time -> latency not hidden at 4 waves/SIMD. To fit 85
// VGPRs: unroll 1 and consume each states-float4 right after its load
// (live set ~70 regs instead of ~120 at unroll 2).

typedef __attribute__((ext_vector_type(8))) short short8;
typedef __attribute__((ext_vector_type(16))) float f32x16;

#define WS_BYTES 36864   // 32768 B W-frags (bf16) + 4096 B bias (f32, transposed)

__device__ __forceinline__ unsigned short f2bf(float x) {
    union { float f; unsigned u; } v; v.f = x;
    return (unsigned short)((v.u + 0x7FFFu + ((v.u >> 16) & 1u)) >> 16);  // RNE
}

// ---- prep: W -> bf16 B-frag order, bias -> transposed f32, into ws ----
// wf[((j*64 + l)*8 + t)] = bf16(W[f][n*32+j]),  l = n + (f>>3)*32, t = f&7
// bf[j*32 + n] = bias[n*32 + j]
__global__ __launch_bounds__(256)
void edgenet_prep(const float* __restrict__ W, const float* __restrict__ bias,
                  void* __restrict__ ws)
{
    const int idx = blockIdx.x * 256 + threadIdx.x;   // 68*256 = 17408 exact
    unsigned short* wf = (unsigned short*)ws;
    float* bf = (float*)((char*)ws + 32768);
    if (idx < 16384) {
        const int f = idx >> 10, c = idx & 1023;
        const int j = c & 31, n = c >> 5;
        const int l = n + ((f >> 3) << 5);
        wf[(((j << 6) + l) << 3) + (f & 7)] = f2bf(W[idx]);
    } else {
        const int q = idx - 16384;                    // q = j*32 + n
        bf[q] = bias[((q & 31) << 5) + (q >> 5)];
    }
}

__global__ __launch_bounds__(512, 3)
void edgenet_main(const float* __restrict__ states,
                  const float* __restrict__ edges,
                  float* __restrict__ out,
                  const void* __restrict__ ws)
{
    __shared__ unsigned char Wb[36864];     // [0,32768): W frags bf16; [32768,): bias f32
    __shared__ float s_lds[4][1024];        // s_lds[tl][j*32 + e]; reused as combine buf

    const int tid  = threadIdx.x;
    const int wave = tid >> 6;
    const int lane = tid & 63;
    const int n    = lane & 31;             // output column i
    const int h    = lane >> 5;
    const int tl    = wave >> 1;            // tile within block (0..3)
    const int jhalf = wave & 1;             // 0: j 0..15, 1: j 16..31
    const int tile  = blockIdx.x * 4 + tl;  // 512 blocks * 4 = 2048 tiles
    const int jbase = jhalf << 4;

    // ---- stage W+bias: linear 16B copy ws -> LDS (2304 chunks) ----
    {
        const char* g = (const char*)ws;
        #pragma unroll
        for (int i = 0; i < 4; ++i) {
            const int off = (i * 512 + tid) * 16;
            *reinterpret_cast<float4*>(&Wb[off]) = *reinterpret_cast<const float4*>(g + off);
        }
        if (tid < 256) {
            const int off = (2048 + tid) * 16;
            *reinterpret_cast<float4*>(&Wb[off]) = *reinterpret_cast<const float4*>(g + off);
        }
    }

    // ---- stage states transposed: 128 threads per tile; s_lds[tl][j*32+e] ----
    {
        const int u = tid & 127, mytl = tid >> 7;
        const int e = u & 31, jq = u >> 5;            // jq = 0..3
        const float* sp = states + ((long long)(blockIdx.x * 4 + mytl) * 32 + e) * 32 + jq * 8;
        const float4 a = *reinterpret_cast<const float4*>(sp);
        const float4 b = *reinterpret_cast<const float4*>(sp + 4);
        float* d = &s_lds[mytl][(jq * 8) * 32 + e];   // stride 32 per j
        d[0 * 32] = a.x; d[1 * 32] = a.y; d[2 * 32] = a.z; d[3 * 32] = a.w;
        d[4 * 32] = b.x; d[5 * 32] = b.y; d[6 * 32] = b.z; d[7 * 32] = b.w;
    }

    // ---- edges A-frag: lane holds edges[tile*32 + n][h*8 .. h*8+7] ----
    const long long erow = (long long)tile * 32 + n;
    const float* ep = edges + erow * 16 + h * 8;
    const float4 ev0 = *reinterpret_cast<const float4*>(ep);
    const float4 ev1 = *reinterpret_cast<const float4*>(ep + 4);
    short8 afrag;
    afrag[0] = (short)f2bf(ev0.x); afrag[1] = (short)f2bf(ev0.y);
    afrag[2] = (short)f2bf(ev0.z); afrag[3] = (short)f2bf(ev0.w);
    afrag[4] = (short)f2bf(ev1.x); afrag[5] = (short)f2bf(ev1.y);
    afrag[6] = (short)f2bf(ev1.z); afrag[7] = (short)f2bf(ev1.w);

    __syncthreads();

    const unsigned short* wl = (const unsigned short*)&Wb[0];
    const float* bl = (const float*)&Wb[32768];
    const float* st = &s_lds[tl][0];

    f32x16 zero16;
    #pragma unroll
    for (int r = 0; r < 16; ++r) zero16[r] = 0.f;

    float p[16];
    #pragma unroll
    for (int r = 0; r < 16; ++r) p[r] = 0.f;

    const int h4 = h << 2;

    #pragma unroll 1
    for (int jj = 0; jj < 16; ++jj) {
        const int j = jbase + jj;
        // B-frag for slice j: one conflict-free ds_read_b128 per lane
        const short8 wfrag = *reinterpret_cast<const short8*>(wl + (((j << 6) + lane) << 3));
        const float bj = bl[(j << 5) + n];

        const f32x16 acc = __builtin_amdgcn_mfma_f32_32x32x16_bf16(afrag, wfrag, zero16, 0, 0, 0);

        // consume each states-float4 right after its load (keeps live set small)
        {
            const float4 s0 = *reinterpret_cast<const float4*>(st + (j << 5) + h4);
            p[0]  = fmaf(fmaxf(acc[0]  + bj, 0.f), s0.x, p[0]);
            p[1]  = fmaf(fmaxf(acc[1]  + bj, 0.f), s0.y, p[1]);
            p[2]  = fmaf(fmaxf(acc[2]  + bj, 0.f), s0.z, p[2]);
            p[3]  = fmaf(fmaxf(acc[3]  + bj, 0.f), s0.w, p[3]);
        }
        {
            const float4 s1 = *reinterpret_cast<const float4*>(st + (j << 5) + h4 + 8);
            p[4]  = fmaf(fmaxf(acc[4]  + bj, 0.f), s1.x, p[4]);
            p[5]  = fmaf(fmaxf(acc[5]  + bj, 0.f), s1.y, p[5]);
            p[6]  = fmaf(fmaxf(acc[6]  + bj, 0.f), s1.z, p[6]);
            p[7]  = fmaf(fmaxf(acc[7]  + bj, 0.f), s1.w, p[7]);
        }
        {
            const float4 s2 = *reinterpret_cast<const float4*>(st + (j << 5) + h4 + 16);
            p[8]  = fmaf(fmaxf(acc[8]  + bj, 0.f), s2.x, p[8]);
            p[9]  = fmaf(fmaxf(acc[9]  + bj, 0.f), s2.y, p[9]);
            p[10] = fmaf(fmaxf(acc[10] + bj, 0.f), s2.z, p[10]);
            p[11] = fmaf(fmaxf(acc[11] + bj, 0.f), s2.w, p[11]);
        }
        {
            const float4 s3 = *reinterpret_cast<const float4*>(st + (j << 5) + h4 + 24);
            p[12] = fmaf(fmaxf(acc[12] + bj, 0.f), s3.x, p[12]);
            p[13] = fmaf(fmaxf(acc[13] + bj, 0.f), s3.y, p[13]);
            p[14] = fmaf(fmaxf(acc[14] + bj, 0.f), s3.z, p[14]);
            p[15] = fmaf(fmaxf(acc[15] + bj, 0.f), s3.w, p[15]);
        }
    }

    // ---- combine the two j-halves via LDS (alias s_lds, dead after loop) ----
    __syncthreads();                         // all s_lds reads done
    float* ob = &s_lds[tl][0];
    if (jhalf == 1) {
        #pragma unroll
        for (int r = 0; r < 16; ++r) {
            const int e = (r & 3) + ((r >> 2) << 3) + h4;
            ob[(e << 5) + n] = p[r];         // bank = n: 2 lanes/bank (h pair) = free
        }
    }
    __syncthreads();
    if (jhalf == 0) {
        float* op = out + ((long long)tile * 32) * 32;
        #pragma unroll
        for (int r = 0; r < 16; ++r) {
            const int e = (r & 3) + ((r >> 2) << 3) + h4;
            op[(e << 5) + n] = p[r] + ob[(e << 5) + n];   // 2 x 128B lines per instr
        }
    }
}

// ---- fallback (ws too small): round-3 kernel (measured 20.9 us) ----
__global__ __launch_bounds__(512, 2)
void edgenet_fallback(const float* __restrict__ states, const float* __restrict__ edges,
                      const float* __restrict__ W, const float* __restrict__ bias,
                      float* __restrict__ out)
{
    __shared__ unsigned short Wlds[16384];
    __shared__ float Blds[1024];
    const int tid  = threadIdx.x;
    const int wave = tid >> 6;
    const int lane = tid & 63;
    const int ecol = lane & 31;
    const int h    = lane >> 5;
    const int tile  = blockIdx.x * 4 + (wave >> 1);
    const int nbase = (wave & 1) << 4;
    const long long row = (long long)tile * 32 + ecol;

    const float* ep = edges + row * 16 + h * 8;
    const float4 ev0 = *reinterpret_cast<const float4*>(ep);
    const float4 ev1 = *reinterpret_cast<const float4*>(ep + 4);
    const float* sp = states + row * 32 + h * 4;
    const float4 sv0 = *reinterpret_cast<const float4*>(sp);
    const float4 sv1 = *reinterpret_cast<const float4*>(sp + 8);
    const float4 sv2 = *reinterpret_cast<const float4*>(sp + 16);
    const float4 sv3 = *reinterpret_cast<const float4*>(sp + 24);

    #pragma unroll
    for (int it = 0; it < 32; ++it) {
        int m = it * 512 + tid;
        int f = m >> 10, c = m & 1023, nn = c >> 5, j = c & 31;
        Wlds[((nn << 6) + j + ((f >> 3) << 5)) * 8 + (f & 7)] = f2bf(W[m]);
    }
    {
        int i0 = tid;
        int r = i0 & 15, hh = (i0 >> 4) & 1, nn = i0 >> 5;
        Blds[i0] = bias[(nn << 5) + (r & 3) + ((r >> 2) << 3) + (hh << 2)];
        int i1 = tid + 512;
        r = i1 & 15; hh = (i1 >> 4) & 1; nn = i1 >> 5;
        Blds[i1] = bias[(nn << 5) + (r & 3) + ((r >> 2) << 3) + (hh << 2)];
    }
    __syncthreads();

    short8 bfrag;
    bfrag[0] = (short)f2bf(ev0.x); bfrag[1] = (short)f2bf(ev0.y);
    bfrag[2] = (short)f2bf(ev0.z); bfrag[3] = (short)f2bf(ev0.w);
    bfrag[4] = (short)f2bf(ev1.x); bfrag[5] = (short)f2bf(ev1.y);
    bfrag[6] = (short)f2bf(ev1.z); bfrag[7] = (short)f2bf(ev1.w);
    const float s[16] = {sv0.x, sv0.y, sv0.z, sv0.w,
                         sv1.x, sv1.y, sv1.z, sv1.w,
                         sv2.x, sv2.y, sv2.z, sv2.w,
                         sv3.x, sv3.y, sv3.z, sv3.w};
    const unsigned short* wl = &Wlds[(((unsigned)nbase << 6) + (unsigned)lane) << 3];
    const float* bb = &Blds[(nbase << 5) + (h << 4)];
    float msg[8];

    #pragma unroll 4
    for (int kk = 0; kk < 8; ++kk) {
        f32x16 acc;
        #pragma unroll
        for (int r = 0; r < 16; ++r) acc[r] = bb[kk * 32 + r];
        const short8 afrag = *reinterpret_cast<const short8*>(wl + kk * 512);
        acc = __builtin_amdgcn_mfma_f32_32x32x16_bf16(afrag, bfrag, acc, 0, 0, 0);
        float p0 = 0.f, p1 = 0.f, p2 = 0.f, p3 = 0.f;
        #pragma unroll
        for (int r = 0; r < 16; r += 4) {
            p0 = fmaf(fmaxf(acc[r+0], 0.f), s[r+0], p0);
            p1 = fmaf(fmaxf(acc[r+1], 0.f), s[r+1], p1);
            p2 = fmaf(fmaxf(acc[r+2], 0.f), s[r+2], p2);
            p3 = fmaf(fmaxf(acc[r+3], 0.f), s[r+3], p3);
        }
        float p = (p0 + p1) + (p2 + p3);
        p += __shfl_xor(p, 32);
        msg[kk] = p;
    }
    if (h == 0) {
        float* op = out + row * 32 + nbase;
        *reinterpret_cast<float4*>(op)     = make_float4(msg[0], msg[1], msg[2], msg[3]);
        *reinterpret_cast<float4*>(op + 4) = make_float4(msg[4], msg[5], msg[6], msg[7]);
    }
    #pragma unroll 4
    for (int kk = 0; kk < 8; ++kk) {
        f32x16 acc;
        #pragma unroll
        for (int r = 0; r < 16; ++r) acc[r] = bb[(8 + kk) * 32 + r];
        const short8 afrag = *reinterpret_cast<const short8*>(wl + (8 + kk) * 512);
        acc = __builtin_amdgcn_mfma_f32_32x32x16_bf16(afrag, bfrag, acc, 0, 0, 0);
        float p0 = 0.f, p1 = 0.f, p2 = 0.f, p3 = 0.f;
        #pragma unroll
        for (int r = 0; r < 16; r += 4) {
            p0 = fmaf(fmaxf(acc[r+0], 0.f), s[r+0], p0);
            p1 = fmaf(fmaxf(acc[r+1], 0.f), s[r+1], p1);
            p2 = fmaf(fmaxf(acc[r+2], 0.f), s[r+2], p2);
            p3 = fmaf(fmaxf(acc[r+3], 0.f), s[r+3], p3);
        }
        float p = (p0 + p1) + (p2 + p3);
        p += __shfl_xor(p, 32);
        msg[kk] = p;
    }
    if (h == 1) {
        float* op = out + row * 32 + nbase + 8;
        *reinterpret_cast<float4*>(op)     = make_float4(msg[0], msg[1], msg[2], msg[3]);
        *reinterpret_cast<float4*>(op + 4) = make_float4(msg[4], msg[5], msg[6], msg[7]);
    }
}

extern "C" void kernel_launch(void* const* d_in, const int* in_sizes, int n_in,
                              void* d_out, int out_size, void* d_ws, size_t ws_size,
                              hipStream_t stream) {
    (void)in_sizes; (void)n_in; (void)out_size;
    const float* states = (const float*)d_in[0];
    const float* edges  = (const float*)d_in[1];
    const float* W      = (const float*)d_in[2];
    const float* bias   = (const float*)d_in[3];
    float* out          = (float*)d_out;

    if (ws_size >= (size_t)WS_BYTES) {
        hipLaunchKernelGGL(edgenet_prep, dim3(68), dim3(256), 0, stream, W, bias, d_ws);
        hipLaunchKernelGGL(edgenet_main, dim3(512), dim3(512), 0, stream,
                           states, edges, out, d_ws);
    } else {
        hipLaunchKernelGGL(edgenet_fallback, dim3(512), dim3(512), 0, stream,
                           states, edges, W, bias, out);
    }
}